// Round 1
// baseline (644.641 us; speedup 1.0000x reference)
//
#include <hip/hip_runtime.h>
#include <math.h>

#define N_ROWS 4096
#define E_DIM  512
#define C_CLS  50257
#define NTILE  197            // ceil(50257/256)
#define NPT    (NTILE * 4)    // partials per row: 197 col-tiles * 4 wave-col-groups
#define COS_M  (-0.6536436208636119f)   // cos(4.0)
#define SIN_M  (-0.7568024953079282f)   // sin(4.0)
#define EPSN   1e-12f

typedef __bf16 bf16x8 __attribute__((ext_vector_type(8)));
typedef float  f32x4  __attribute__((ext_vector_type(4)));
typedef unsigned short ushort8 __attribute__((ext_vector_type(8)));

__device__ inline unsigned short f2bf(float f) {
  unsigned int u = __float_as_uint(f);
  u += 0x7FFFu + ((u >> 16) & 1u);     // round-to-nearest-even
  return (unsigned short)(u >> 16);
}

// w row L2-normalize, wave-private (no barriers): 4 rows/block, 1 wave/row.
__global__ __launch_bounds__(256) void k_norm_w(const float* __restrict__ src,
                                                unsigned short* __restrict__ dst) {
  int row = blockIdx.x * 4 + (threadIdx.x >> 6);
  if (row >= C_CLS) return;
  int lane = threadIdx.x & 63;
  const float4* p = (const float4*)(src + (size_t)row * E_DIM);
  float4 v0 = p[lane * 2], v1 = p[lane * 2 + 1];
  float ss = v0.x*v0.x + v0.y*v0.y + v0.z*v0.z + v0.w*v0.w
           + v1.x*v1.x + v1.y*v1.y + v1.z*v1.z + v1.w*v1.w;
  #pragma unroll
  for (int m = 32; m > 0; m >>= 1) ss += __shfl_xor(ss, m, 64);
  float inv = 1.0f / fmaxf(sqrtf(ss), EPSN);
  ushort8 o;
  o[0]=f2bf(v0.x*inv); o[1]=f2bf(v0.y*inv); o[2]=f2bf(v0.z*inv); o[3]=f2bf(v0.w*inv);
  o[4]=f2bf(v1.x*inv); o[5]=f2bf(v1.y*inv); o[6]=f2bf(v1.z*inv); o[7]=f2bf(v1.w*inv);
  *(ushort8*)(dst + (size_t)row * E_DIM + lane * 8) = o;
}

// x row L2-normalize + precise fp32 target cosine (fused). 1 block/row, 256 thr.
__global__ __launch_bounds__(256) void k_norm_x(const float* __restrict__ x,
                                                const float* __restrict__ w,
                                                const int* __restrict__ label,
                                                unsigned short* __restrict__ nx,
                                                float* __restrict__ tv) {
  int row = blockIdx.x;
  int lab = label[row];
  int tid = threadIdx.x;
  const float2* px = (const float2*)(x + (size_t)row * E_DIM);
  const float2* pw = (const float2*)(w + (size_t)lab * E_DIM);
  float2 a = px[tid], b = pw[tid];
  float sx = a.x*a.x + a.y*a.y;
  float sw = b.x*b.x + b.y*b.y;
  float sd = a.x*b.x + a.y*b.y;
  #pragma unroll
  for (int off = 32; off > 0; off >>= 1) {
    sx += __shfl_down(sx, off, 64);
    sw += __shfl_down(sw, off, 64);
    sd += __shfl_down(sd, off, 64);
  }
  __shared__ float sb[3][4];
  if ((tid & 63) == 0) {
    sb[0][tid >> 6] = sx; sb[1][tid >> 6] = sw; sb[2][tid >> 6] = sd;
  }
  __syncthreads();
  float SX = sb[0][0] + sb[0][1] + sb[0][2] + sb[0][3];
  float inv = 1.0f / fmaxf(sqrtf(SX), EPSN);
  ushort2 o;
  o.x = f2bf(a.x * inv);
  o.y = f2bf(a.y * inv);
  ((ushort2*)(nx + (size_t)row * E_DIM))[tid] = o;
  if (tid == 0) {
    float SW = sb[1][0] + sb[1][1] + sb[1][2] + sb[1][3];
    float SD = sb[2][0] + sb[2][1] + sb[2][2] + sb[2][3];
    tv[row] = SD / (fmaxf(sqrtf(SX), EPSN) * fmaxf(sqrtf(SW), EPSN));
  }
}

// ---------------------------------------------------------------------------
// 256x256-tile GEMM (cos = nx.nw^T) + fused exp-sum, 8-phase schedule (T3+T4+T5).
//
// Geometry: BM=BN=256, BK=64, 512 thr = 8 waves (wm in 0..1 rows, wn in 0..3
// cols); per-wave output 128x64 = acc[8][4] 16x16 frags (128 VGPR).
// LDS 128 KiB: A = 2 bufs x (16 rg x 2 kf) chunks, B same; chunk = 64 lanes x
// 16 B in exact MFMA fragment order (lane (q,l15) holds row c*16+l15, elems
// kf*32+q*8..+7) -> all ds_read_b128 are lane*16 linear = 0 bank conflicts,
// and global_load_lds (linear dst) stages it by pre-swizzling the per-lane
// GLOBAL address (m173 pattern).
//
// Staging unit = one (matrix, kf) k-half of a K-tile = 16 chunks = 16 KB =
// 2 global_load_lds per thread (wave w stages chunks 2w, 2w+1).
// Per K-tile T (buf b=T&1), 4 phases:
//   ph0 (kf0,rh0): read A(b,k0) rg wm*8+0..3 + B(b,k0) all -> stage (T+1,A,k1)
//   ph1 (kf0,rh1): read A(b,k0) rg wm*8+4..7 (B reused)    -> stage (T+1,B,k1)
//   ph2 (kf1,rh0): read A(b,k1) + B(b,k1)                  -> stage (T+2,A,k0)
//   ph3 (kf1,rh1): read A(b,k1)                            -> stage (T+2,B,k0)
//                  + s_waitcnt vmcnt(4)  (counted: the 2 units just staged may
//                    stay in flight across the barrier; never 0 in steady state)
// Each phase: {ds_reads, stage, s_barrier, lgkmcnt(0), setprio(1), 16 MFMA,
// setprio(0), s_barrier}. Safety: stage targets are disjoint from that phase's
// read regions; a region is only re-staged >=1 phase after its last read (reads
// retire at that phase's lgkmcnt(0), before the trailing barrier all waves
// pass); vmcnt(4)-before-barrier guarantees cross-wave data arrival.
// Tail: T=6 uses vmcnt(0) (its ph2/3 stage nothing, so (7,k1) must drain).
// ---------------------------------------------------------------------------
#define GLDS(gp, lp) __builtin_amdgcn_global_load_lds( \
    (const __attribute__((address_space(1))) void*)(gp), \
    (__attribute__((address_space(3))) void*)(lp), 16, 0, 0)

#define PHASE(B2KF, RH, LOADB, STAGE_STMT, WAIT_STMT) do { \
  _Pragma("unroll") \
  for (int i = 0; i < 4; i++) \
    afr[i] = *(const bf16x8*)(ldsA + (unsigned)((B2KF) * 16 + wm * 8 + (RH) * 4 + i) * 1024u + lane16); \
  if (LOADB) { \
    _Pragma("unroll") \
    for (int j = 0; j < 4; j++) \
      bfr[j] = *(const bf16x8*)(ldsB + (unsigned)((B2KF) * 16 + wn * 4 + j) * 1024u + lane16); \
  } \
  STAGE_STMT; \
  WAIT_STMT; \
  __builtin_amdgcn_s_barrier(); \
  asm volatile("s_waitcnt lgkmcnt(0)" ::: "memory"); \
  __builtin_amdgcn_s_setprio(1); \
  _Pragma("unroll") \
  for (int i = 0; i < 4; i++) { \
    _Pragma("unroll") \
    for (int j = 0; j < 4; j++) \
      acc[(RH) * 4 + i][j] = __builtin_amdgcn_mfma_f32_16x16x32_bf16( \
          afr[i], bfr[j], acc[(RH) * 4 + i][j], 0, 0, 0); \
  } \
  __builtin_amdgcn_s_setprio(0); \
  __builtin_amdgcn_s_barrier(); \
} while (0)

__global__ __launch_bounds__(512, 2) void k_gemm(const unsigned short* __restrict__ nx,
                                                 const unsigned short* __restrict__ nw,
                                                 const int* __restrict__ label,
                                                 float* __restrict__ pl,
                                                 float* __restrict__ tbf) {
  __shared__ unsigned char ldsA[65536];   // 2 bufs x 2 kf x 16 rg x 1 KB
  __shared__ unsigned char ldsB[65536];

  const int rtile = blockIdx.x;           // 0..15 fastest -> B-panel reuse in L2
  const int ctile = blockIdx.y;           // 0..196
  const int tid  = threadIdx.x;
  const int wave = tid >> 6;
  const int lane = tid & 63;
  const int q    = lane >> 4;
  const int l15  = lane & 15;
  const int wm   = wave >> 2;             // 0..1 row half
  const int wn   = wave & 3;              // 0..3 col quarter
  const int rowTile = rtile * 256;
  const int colTile = ctile * 256;
  const unsigned lane16 = (unsigned)lane * 16u;

  // Staging sources: wave w stages chunks {2w, 2w+1}; lane supplies the exact
  // fragment element (row cg*16+l15, k-elems q*8..+7) -> LDS lands linear.
  const unsigned short* gA0 = nx + (size_t)(rowTile + wave * 32 + l15) * E_DIM + q * 8;
  int cls0 = colTile + wave * 32 + l15;      if (cls0 >= C_CLS) cls0 = C_CLS - 1;
  int cls1 = colTile + wave * 32 + 16 + l15; if (cls1 >= C_CLS) cls1 = C_CLS - 1;
  const unsigned short* gB0 = nw + (size_t)cls0 * E_DIM + q * 8;
  const unsigned short* gB1 = nw + (size_t)cls1 * E_DIM + q * 8;

  auto stageA = [&](int Tt, int kf) {
    unsigned b = (unsigned)((((Tt & 1) * 2 + kf) * 16 + wave * 2) * 1024);
    const unsigned short* g = gA0 + Tt * 64 + kf * 32;
    GLDS(g, ldsA + b);
    GLDS(g + 16 * E_DIM, ldsA + b + 1024);
  };
  auto stageB = [&](int Tt, int kf) {
    unsigned b = (unsigned)((((Tt & 1) * 2 + kf) * 16 + wave * 2) * 1024);
    int ko = Tt * 64 + kf * 32;
    GLDS(gB0 + ko, ldsB + b);
    GLDS(gB1 + ko, ldsB + b + 1024);
  };

  // Prologue: K-tile 0 fully + K-tile 1 k0-units (12 loads); allow last 4
  // (the (1,*,k0) units, not read until T=1) to stay in flight.
  stageA(0, 0); stageB(0, 0);
  stageA(0, 1); stageB(0, 1);
  stageA(1, 0); stageB(1, 0);
  asm volatile("s_waitcnt vmcnt(4)" ::: "memory");
  __builtin_amdgcn_s_barrier();

  f32x4 acc[8][4] = {};

  #pragma unroll
  for (int T = 0; T < 8; T++) {
    const int b2 = (T & 1) * 2;
    bf16x8 afr[4], bfr[4];
    PHASE(b2 + 0, 0, 1, { if (T + 1 < 8) stageA(T + 1, 1); }, ((void)0));
    PHASE(b2 + 0, 1, 0, { if (T + 1 < 8) stageB(T + 1, 1); }, ((void)0));
    PHASE(b2 + 1, 0, 1, { if (T + 2 < 8) stageA(T + 2, 0); }, ((void)0));
    PHASE(b2 + 1, 1, 0, { if (T + 2 < 8) stageB(T + 2, 0); },
          { if (T + 2 < 8) { asm volatile("s_waitcnt vmcnt(4)" ::: "memory"); }
            else           { asm volatile("s_waitcnt vmcnt(0)" ::: "memory"); } });
  }

  // Epilogue: C/D frag layout row = 4*q + r, col = l15. Wave covers rows
  // [rowTile + wm*128, +128), cols [colTile + wn*64, +64).
  const int colW = colTile + wn * 64;
  #pragma unroll
  for (int ib = 0; ib < 8; ib++) {
    #pragma unroll
    for (int r = 0; r < 4; r++) {
      int grow = rowTile + wm * 128 + ib * 16 + 4 * q + r;
      int lab = label[grow];
      float e = 0.f;
      #pragma unroll
      for (int j = 0; j < 4; j++) {
        int col = colW + j * 16 + l15;
        float v = acc[ib][j][r];
        if (col < C_CLS) {
          e += __expf(v);
          if (col == lab) tbf[grow] = v;   // bf16-GEMM cos at label position
        }
      }
      #pragma unroll
      for (int m = 1; m < 16; m <<= 1) e += __shfl_xor(e, m, 64);
      if (l15 == 0) pl[(size_t)grow * NPT + (size_t)ctile * 4 + wn] = e;
    }
  }
}

// Sum per-tile exp-sums -> row denominator, swap in margin logit, mean-reduce.
__global__ __launch_bounds__(256) void k_reduce(const float* __restrict__ pl,
                                               const float* __restrict__ tv,
                                               const float* __restrict__ tbf,
                                               float* __restrict__ out) {
  int row = blockIdx.x;
  int tid = threadIdx.x;
  float s = 0.f;
  for (int j = tid; j < NPT; j += 256) s += pl[(size_t)row * NPT + j];
  __shared__ float sb[256];
  sb[tid] = s;
  __syncthreads();
  for (int k = 128; k > 0; k >>= 1) {
    if (tid < k) sb[tid] += sb[tid + k];
    __syncthreads();
  }
  if (tid == 0) {
    float S = sb[0];
    float t = tv[row];
    float tb = tbf[row];
    float sint = sqrtf(fmaxf(0.f, 1.f - t * t));
    float cosm = t * COS_M - sint * SIN_M;
    float Sp = S - __expf(tb) + __expf(cosm);   // replace target logit
    float loss = logf(Sp) - cosm;
    atomicAdd(out, loss * (1.0f / N_ROWS));
  }
}

extern "C" void kernel_launch(void* const* d_in, const int* in_sizes, int n_in,
                              void* d_out, int out_size, void* d_ws, size_t ws_size,
                              hipStream_t stream) {
  const float* x = (const float*)d_in[0];
  const int* label = (const int*)d_in[1];
  const float* w = (const float*)d_in[2];
  float* out = (float*)d_out;
  char* ws = (char*)d_ws;

  size_t off = 0;
  unsigned short* nx = (unsigned short*)(ws + off); off += (size_t)N_ROWS * E_DIM * 2;  // 4 MB
  unsigned short* nw = (unsigned short*)(ws + off); off += (size_t)C_CLS * E_DIM * 2;   // 51.5 MB
  float* tv  = (float*)(ws + off); off += (size_t)N_ROWS * 4;
  float* tbf = (float*)(ws + off); off += (size_t)N_ROWS * 4;
  float* pl  = (float*)(ws + off); off += (size_t)N_ROWS * NPT * 4;                     // 12.9 MB

  hipMemsetAsync(d_out, 0, sizeof(float), stream);
  k_norm_w<<<(C_CLS + 3) / 4, 256, 0, stream>>>(w, nw);
  k_norm_x<<<N_ROWS, 256, 0, stream>>>(x, w, label, nx, tv);
  dim3 g(N_ROWS / 256, NTILE);
  k_gemm<<<g, 512, 0, stream>>>(nx, nw, label, pl, tbf);
  k_reduce<<<N_ROWS, 256, 0, stream>>>(pl, tv, tbf, out);
}

// Round 2
// 513.432 us; speedup vs baseline: 1.2556x; 1.2556x over previous
//
#include <hip/hip_runtime.h>
#include <math.h>

#define N_ROWS 4096
#define E_DIM  512
#define C_CLS  50257
#define NCH    786            // ceil(50257/64) col chunks of 64
#define COS_M  (-0.6536436208636119f)   // cos(4.0)
#define SIN_M  (-0.7568024953079282f)   // sin(4.0)
#define EPSN   1e-12f

typedef __bf16 bf16x8 __attribute__((ext_vector_type(8)));
typedef float  f32x4  __attribute__((ext_vector_type(4)));
typedef unsigned short ushort8 __attribute__((ext_vector_type(8)));

__device__ inline unsigned short f2bf(float f) {
  unsigned int u = __float_as_uint(f);
  u += 0x7FFFu + ((u >> 16) & 1u);     // round-to-nearest-even
  return (unsigned short)(u >> 16);
}

// w row L2-normalize, wave-private (no barriers): 4 rows/block, 1 wave/row.
__global__ __launch_bounds__(256) void k_norm_w(const float* __restrict__ src,
                                                unsigned short* __restrict__ dst) {
  int row = blockIdx.x * 4 + (threadIdx.x >> 6);
  if (row >= C_CLS) return;
  int lane = threadIdx.x & 63;
  const float4* p = (const float4*)(src + (size_t)row * E_DIM);
  float4 v0 = p[lane * 2], v1 = p[lane * 2 + 1];
  float ss = v0.x*v0.x + v0.y*v0.y + v0.z*v0.z + v0.w*v0.w
           + v1.x*v1.x + v1.y*v1.y + v1.z*v1.z + v1.w*v1.w;
  #pragma unroll
  for (int m = 32; m > 0; m >>= 1) ss += __shfl_xor(ss, m, 64);
  float inv = 1.0f / fmaxf(sqrtf(ss), EPSN);
  ushort8 o;
  o[0]=f2bf(v0.x*inv); o[1]=f2bf(v0.y*inv); o[2]=f2bf(v0.z*inv); o[3]=f2bf(v0.w*inv);
  o[4]=f2bf(v1.x*inv); o[5]=f2bf(v1.y*inv); o[6]=f2bf(v1.z*inv); o[7]=f2bf(v1.w*inv);
  *(ushort8*)(dst + (size_t)row * E_DIM + lane * 8) = o;
}

// x row L2-normalize + precise fp32 target cosine (fused). 1 block/row, 256 thr.
__global__ __launch_bounds__(256) void k_norm_x(const float* __restrict__ x,
                                                const float* __restrict__ w,
                                                const int* __restrict__ label,
                                                unsigned short* __restrict__ nx,
                                                float* __restrict__ tv) {
  int row = blockIdx.x;
  int lab = label[row];
  int tid = threadIdx.x;
  const float2* px = (const float2*)(x + (size_t)row * E_DIM);
  const float2* pw = (const float2*)(w + (size_t)lab * E_DIM);
  float2 a = px[tid], b = pw[tid];
  float sx = a.x*a.x + a.y*a.y;
  float sw = b.x*b.x + b.y*b.y;
  float sd = a.x*b.x + a.y*b.y;
  #pragma unroll
  for (int off = 32; off > 0; off >>= 1) {
    sx += __shfl_down(sx, off, 64);
    sw += __shfl_down(sw, off, 64);
    sd += __shfl_down(sd, off, 64);
  }
  __shared__ float sb[3][4];
  if ((tid & 63) == 0) {
    sb[0][tid >> 6] = sx; sb[1][tid >> 6] = sw; sb[2][tid >> 6] = sd;
  }
  __syncthreads();
  float SX = sb[0][0] + sb[0][1] + sb[0][2] + sb[0][3];
  float inv = 1.0f / fmaxf(sqrtf(SX), EPSN);
  ushort2 o;
  o.x = f2bf(a.x * inv);
  o.y = f2bf(a.y * inv);
  ((ushort2*)(nx + (size_t)row * E_DIM))[tid] = o;
  if (tid == 0) {
    float SW = sb[1][0] + sb[1][1] + sb[1][2] + sb[1][3];
    float SD = sb[2][0] + sb[2][1] + sb[2][2] + sb[2][3];
    tv[row] = SD / (fmaxf(sqrtf(SX), EPSN) * fmaxf(sqrtf(SW), EPSN));
  }
}

// ---------------------------------------------------------------------------
// Persistent column-streaming GEMM for flat shape (K=512 resident in regs).
//
// Grid = 16 rtiles x 16 col-groups = 256 blocks = exactly 1 block/CU, ONE
// generation (no churn). Block = 8 waves x 64 = 512 thr; BM = 256 rows
// (wave w owns rows [wave*32, +32)); per-wave A-slab (32 rows x K=512 bf16)
// lives in REGISTERS for the whole block: a[2][16] bf16x8 = 128 VGPR,
// loaded once. acc[2][4] f32x4 = 32 VGPR. ~210 VGPR total @ 2 waves/SIMD.
//
// B streams as 64-col x full-K chunks (64 KB) through a 2x64 KB LDS double
// buffer via global_load_lds (8 per thread per chunk; wave-uniform dst base,
// lane-linear 16 B, MFMA-fragment order -> reads are base+lane*16 linear,
// 0 bank conflicts). Depth-1 prefetch: stage chunk c+1 at the top of chunk c,
// compute 16 K-steps x 8 MFMA (NO internal barriers; compiler schedules),
// per-chunk epilogue (exp + 16-lane reduce + partial store, register-private),
// then ONE __syncthreads() (its vmcnt(0) is free: prefetch had ~5K cycles to
// land; its lgkmcnt(0) retires this wave's buf-p reads before anyone stages
// chunk c+2 into buf p). Labels hoisted to regs (8/lane) at block start.
// ---------------------------------------------------------------------------
#define GLDS(gp, lp) __builtin_amdgcn_global_load_lds( \
    (const __attribute__((address_space(1))) void*)(gp), \
    (__attribute__((address_space(3))) void*)(lp), 16, 0, 0)

__global__ __launch_bounds__(512, 2) void k_gemm(const unsigned short* __restrict__ nx,
                                                 const unsigned short* __restrict__ nw,
                                                 const int* __restrict__ label,
                                                 float* __restrict__ pl,
                                                 float* __restrict__ tbf) {
  __shared__ unsigned char ldsB[2][65536];   // 2 x (64 cols x 512 k x 2 B)

  const int rtile = blockIdx.x;              // 0..15
  const int grp   = blockIdx.y;              // 0..15
  const int c0    = grp * 49 + (grp < 2 ? grp : 2);   // chunk range [c0, c1)
  const int c1    = c0 + 49 + (grp < 2 ? 1 : 0);      // groups 0,1 take 50

  const int tid  = threadIdx.x;
  const int wave = tid >> 6;
  const int lane = tid & 63;
  const int q    = lane >> 4;
  const int l15  = lane & 15;
  const int row0 = rtile * 256 + wave * 32;  // wave's first output row

  // Stage chunk c into LDS buffer p. Chunk layout: 64 1-KB fragment chunks,
  // index ch=(cf<<4)|kf covers cols [cf*16,+16) x k [kf*32,+32); lane (q,l15)
  // supplies col cf*16+l15, k kf*32+q*8..+7 (16 B) -> lands at base+lane*16.
  auto stageB = [&](int c, int p) {
    unsigned cb = (unsigned)c * 64u;
    #pragma unroll
    for (int i = 0; i < 8; i++) {
      int ch = wave * 8 + i;                 // wave-uniform
      unsigned col = cb + (unsigned)(((ch >> 4) << 4) + l15);
      if (col >= C_CLS) col = C_CLS - 1;     // clamp; masked in epilogue
      unsigned off = col * (unsigned)E_DIM + (unsigned)((ch & 15) * 32 + q * 8);
      GLDS(nw + off, &ldsB[p][ch * 1024]);
    }
  };

  // Issue first B-chunk stage, then load A-slab + labels while it flies.
  stageB(c0, c0 & 1);

  bf16x8 a[2][16];                           // 32 rows x K=512, 128 VGPR
  #pragma unroll
  for (int rf = 0; rf < 2; rf++)
    #pragma unroll
    for (int kf = 0; kf < 16; kf++)
      a[rf][kf] = *(const bf16x8*)(nx + (size_t)(row0 + rf * 16 + l15) * E_DIM
                                      + kf * 32 + q * 8);
  int labs[8];                               // labels of this lane's 8 rows
  #pragma unroll
  for (int rf = 0; rf < 2; rf++)
    #pragma unroll
    for (int r = 0; r < 4; r++)
      labs[rf * 4 + r] = label[row0 + rf * 16 + 4 * q + r];

  __syncthreads();                           // chunk c0 landed everywhere

  for (int c = c0; c < c1; ++c) {
    const int p = c & 1;
    if (c + 1 < c1) stageB(c + 1, p ^ 1);    // depth-1 prefetch (other buffer)

    f32x4 acc[2][4] = {};
    const unsigned char* bb = &ldsB[p][0];
    #pragma unroll
    for (int ks = 0; ks < 16; ks++) {
      bf16x8 bfr[4];
      #pragma unroll
      for (int cf = 0; cf < 4; cf++)
        bfr[cf] = *(const bf16x8*)(bb + (unsigned)((cf * 16 + ks) * 1024) + (unsigned)lane * 16u);
      #pragma unroll
      for (int rf = 0; rf < 2; rf++)
        #pragma unroll
        for (int cf = 0; cf < 4; cf++)
          acc[rf][cf] = __builtin_amdgcn_mfma_f32_16x16x32_bf16(
              a[rf][ks], bfr[cf], acc[rf][cf], 0, 0, 0);
    }

    // Per-chunk epilogue: C/D frag layout row = 4q + r, col = l15.
    const int ccol = c * 64;
    #pragma unroll
    for (int rf = 0; rf < 2; rf++) {
      #pragma unroll
      for (int r = 0; r < 4; r++) {
        int grow = row0 + rf * 16 + 4 * q + r;
        int lab = labs[rf * 4 + r];
        float e = 0.f;
        #pragma unroll
        for (int cf = 0; cf < 4; cf++) {
          int col = ccol + cf * 16 + l15;
          float v = acc[rf][cf][r];
          if (col < C_CLS) {
            e += __expf(v);
            if (col == lab) tbf[grow] = v;   // bf16-GEMM cos at label position
          }
        }
        #pragma unroll
        for (int m = 1; m < 16; m <<= 1) e += __shfl_xor(e, m, 64);
        if (l15 == 0) pl[(size_t)grow * NCH + c] = e;
      }
    }

    __syncthreads();   // vmcnt(0): c+1 landed (free, ~5K cyc elapsed);
                       // lgkmcnt(0): my buf-p reads retired; barrier: all waves
                       // done with buf p -> next iter may stage c+2 into it.
  }
}

// Sum per-chunk exp-sums -> row denominator, swap in margin logit, mean-reduce.
__global__ __launch_bounds__(256) void k_reduce(const float* __restrict__ pl,
                                               const float* __restrict__ tv,
                                               const float* __restrict__ tbf,
                                               float* __restrict__ out) {
  int row = blockIdx.x;
  int tid = threadIdx.x;
  float s = 0.f;
  for (int j = tid; j < NCH; j += 256) s += pl[(size_t)row * NCH + j];
  __shared__ float sb[256];
  sb[tid] = s;
  __syncthreads();
  for (int k = 128; k > 0; k >>= 1) {
    if (tid < k) sb[tid] += sb[tid + k];
    __syncthreads();
  }
  if (tid == 0) {
    float S = sb[0];
    float t = tv[row];
    float tb = tbf[row];
    float sint = sqrtf(fmaxf(0.f, 1.f - t * t));
    float cosm = t * COS_M - sint * SIN_M;
    float Sp = S - __expf(tb) + __expf(cosm);   // replace target logit
    float loss = logf(Sp) - cosm;
    atomicAdd(out, loss * (1.0f / N_ROWS));
  }
}

extern "C" void kernel_launch(void* const* d_in, const int* in_sizes, int n_in,
                              void* d_out, int out_size, void* d_ws, size_t ws_size,
                              hipStream_t stream) {
  const float* x = (const float*)d_in[0];
  const int* label = (const int*)d_in[1];
  const float* w = (const float*)d_in[2];
  float* out = (float*)d_out;
  char* ws = (char*)d_ws;

  size_t off = 0;
  unsigned short* nx = (unsigned short*)(ws + off); off += (size_t)N_ROWS * E_DIM * 2;  // 4 MB
  unsigned short* nw = (unsigned short*)(ws + off); off += (size_t)C_CLS * E_DIM * 2;   // 51.5 MB
  float* tv  = (float*)(ws + off); off += (size_t)N_ROWS * 4;
  float* tbf = (float*)(ws + off); off += (size_t)N_ROWS * 4;
  float* pl  = (float*)(ws + off); off += (size_t)N_ROWS * NCH * 4;                     // 12.9 MB

  hipMemsetAsync(d_out, 0, sizeof(float), stream);
  k_norm_w<<<(C_CLS + 3) / 4, 256, 0, stream>>>(w, nw);
  k_norm_x<<<N_ROWS, 256, 0, stream>>>(x, w, label, nx, tv);
  dim3 g(16, 16);
  k_gemm<<<g, 512, 0, stream>>>(nx, nw, label, pl, tbf);
  k_reduce<<<N_ROWS, 256, 0, stream>>>(pl, tv, tbf, out);
}

// Round 3
// 397.116 us; speedup vs baseline: 1.6233x; 1.2929x over previous
//
#include <hip/hip_runtime.h>
#include <math.h>

#define N_ROWS 4096
#define E_DIM  512
#define C_CLS  50257
#define NCH    786            // ceil(50257/64) col chunks of 64
#define NGRP   16             // col groups (blockIdx.y); pl = [N_ROWS][NGRP]
#define COS_M  (-0.6536436208636119f)   // cos(4.0)
#define SIN_M  (-0.7568024953079282f)   // sin(4.0)
#define EPSN   1e-12f

typedef __bf16 bf16x8 __attribute__((ext_vector_type(8)));
typedef float  f32x4  __attribute__((ext_vector_type(4)));
typedef unsigned short ushort8 __attribute__((ext_vector_type(8)));

__device__ inline unsigned short f2bf(float f) {
  unsigned int u = __float_as_uint(f);
  u += 0x7FFFu + ((u >> 16) & 1u);     // round-to-nearest-even
  return (unsigned short)(u >> 16);
}

// w row L2-normalize, wave-private (no barriers): 4 rows/block, 1 wave/row.
__global__ __launch_bounds__(256) void k_norm_w(const float* __restrict__ src,
                                                unsigned short* __restrict__ dst) {
  int row = blockIdx.x * 4 + (threadIdx.x >> 6);
  if (row >= C_CLS) return;
  int lane = threadIdx.x & 63;
  const float4* p = (const float4*)(src + (size_t)row * E_DIM);
  float4 v0 = p[lane * 2], v1 = p[lane * 2 + 1];
  float ss = v0.x*v0.x + v0.y*v0.y + v0.z*v0.z + v0.w*v0.w
           + v1.x*v1.x + v1.y*v1.y + v1.z*v1.z + v1.w*v1.w;
  #pragma unroll
  for (int m = 32; m > 0; m >>= 1) ss += __shfl_xor(ss, m, 64);
  float inv = 1.0f / fmaxf(sqrtf(ss), EPSN);
  ushort8 o;
  o[0]=f2bf(v0.x*inv); o[1]=f2bf(v0.y*inv); o[2]=f2bf(v0.z*inv); o[3]=f2bf(v0.w*inv);
  o[4]=f2bf(v1.x*inv); o[5]=f2bf(v1.y*inv); o[6]=f2bf(v1.z*inv); o[7]=f2bf(v1.w*inv);
  *(ushort8*)(dst + (size_t)row * E_DIM + lane * 8) = o;
}

// x row L2-normalize + precise fp32 target cosine (fused). 1 block/row, 256 thr.
__global__ __launch_bounds__(256) void k_norm_x(const float* __restrict__ x,
                                                const float* __restrict__ w,
                                                const int* __restrict__ label,
                                                unsigned short* __restrict__ nx,
                                                float* __restrict__ tv) {
  int row = blockIdx.x;
  int lab = label[row];
  int tid = threadIdx.x;
  const float2* px = (const float2*)(x + (size_t)row * E_DIM);
  const float2* pw = (const float2*)(w + (size_t)lab * E_DIM);
  float2 a = px[tid], b = pw[tid];
  float sx = a.x*a.x + a.y*a.y;
  float sw = b.x*b.x + b.y*b.y;
  float sd = a.x*b.x + a.y*b.y;
  #pragma unroll
  for (int off = 32; off > 0; off >>= 1) {
    sx += __shfl_down(sx, off, 64);
    sw += __shfl_down(sw, off, 64);
    sd += __shfl_down(sd, off, 64);
  }
  __shared__ float sb[3][4];
  if ((tid & 63) == 0) {
    sb[0][tid >> 6] = sx; sb[1][tid >> 6] = sw; sb[2][tid >> 6] = sd;
  }
  __syncthreads();
  float SX = sb[0][0] + sb[0][1] + sb[0][2] + sb[0][3];
  float inv = 1.0f / fmaxf(sqrtf(SX), EPSN);
  ushort2 o;
  o.x = f2bf(a.x * inv);
  o.y = f2bf(a.y * inv);
  ((ushort2*)(nx + (size_t)row * E_DIM))[tid] = o;
  if (tid == 0) {
    float SW = sb[1][0] + sb[1][1] + sb[1][2] + sb[1][3];
    float SD = sb[2][0] + sb[2][1] + sb[2][2] + sb[2][3];
    tv[row] = SD / (fmaxf(sqrtf(SX), EPSN) * fmaxf(sqrtf(SW), EPSN));
  }
}

// ---------------------------------------------------------------------------
// Persistent column-streaming GEMM (K=512 register-resident A) + deferred
// exp-sum reduction.
//
// Grid = 16 rtiles x 16 col-groups = 256 blocks = 1 block/CU, one generation.
// Wave owns 32 rows; A-slab a[2][16] (32 rows x K=512 bf16) = 128 VGPR is
// PINNED via empty inline-asm value-laundering (round-2 lesson: without the
// pin, the register allocator sinks the loop-invariant A loads into the chunk
// loop -> 64 KB/wave/chunk reloaded from L2, ~9K cyc/chunk; VGPR_Count=124
// was the tell). acc[2][4] + e[8] + frags ~= 220 VGPR total, 2 waves/SIMD
// (LDS-capped anyway).
//
// B streams as 64-col x full-K 64 KB chunks through a 2x64 KB LDS double
// buffer via global_load_lds (fragment-ordered, lane-linear 16 B dst -> all
// ds_read_b128 are base+lane*16, 0 bank conflicts). Depth-1 prefetch, ONE
// __syncthreads per chunk (vmcnt(0) drain is covered: the prefetch has the
// whole ~7K-cycle chunk to land from L2/L3).
//
// Per-chunk epilogue is ONLY 32 exp + 32 add into per-lane partials e[8]
// (plus the rare label-hit store). The 16-lane shfl reduce + pl store happen
// ONCE per block: pl = [4096][16] (256 KB), killing the round-2 partial-line
// RMW amplification (WRITE_SIZE 108 MB -> ~MBs).
// ---------------------------------------------------------------------------
#define GLDS(gp, lp) __builtin_amdgcn_global_load_lds( \
    (const __attribute__((address_space(1))) void*)(gp), \
    (__attribute__((address_space(3))) void*)(lp), 16, 0, 0)

__global__ __launch_bounds__(512, 2) void k_gemm(const unsigned short* __restrict__ nx,
                                                 const unsigned short* __restrict__ nw,
                                                 const int* __restrict__ label,
                                                 float* __restrict__ pl,
                                                 float* __restrict__ tbf) {
  __shared__ unsigned char ldsB[2][65536];   // 2 x (64 cols x 512 k x 2 B)

  const int rtile = blockIdx.x;              // 0..15
  const int grp   = blockIdx.y;              // 0..15
  const int c0    = grp * 49 + (grp < 2 ? grp : 2);   // chunk range [c0, c1)
  const int c1    = c0 + 49 + (grp < 2 ? 1 : 0);      // groups 0,1 take 50

  const int tid  = threadIdx.x;
  const int wave = tid >> 6;
  const int lane = tid & 63;
  const int q    = lane >> 4;
  const int l15  = lane & 15;
  const int row0 = rtile * 256 + wave * 32;  // wave's first output row

  // Stage chunk c into LDS buffer p. Chunk layout: 64 1-KB fragment chunks,
  // index ch=(cf<<4)|kf covers cols [cf*16,+16) x k [kf*32,+32); lane (q,l15)
  // supplies col cf*16+l15, k kf*32+q*8..+7 (16 B) -> lands at base+lane*16.
  auto stageB = [&](int c, int p) {
    unsigned cb = (unsigned)c * 64u;
    #pragma unroll
    for (int i = 0; i < 8; i++) {
      int ch = wave * 8 + i;                 // wave-uniform
      unsigned col = cb + (unsigned)(((ch >> 4) << 4) + l15);
      if (col >= C_CLS) col = C_CLS - 1;     // clamp; masked in epilogue
      unsigned off = col * (unsigned)E_DIM + (unsigned)((ch & 15) * 32 + q * 8);
      GLDS(nw + off, &ldsB[p][ch * 1024]);
    }
  };

  // Issue first B-chunk stage, then load A-slab + labels while it flies.
  stageB(c0, c0 & 1);

  bf16x8 a[2][16];                           // 32 rows x K=512, 128 VGPR
  #pragma unroll
  for (int rf = 0; rf < 2; rf++)
    #pragma unroll
    for (int kf = 0; kf < 16; kf++)
      a[rf][kf] = *(const bf16x8*)(nx + (size_t)(row0 + rf * 16 + l15) * E_DIM
                                      + kf * 32 + q * 8);
  // PIN the A-slab: launder each fragment through empty asm so the values
  // become opaque (not rematerializable by reloading from nx). Forces true
  // register residency across the chunk loop.
  #pragma unroll
  for (int rf = 0; rf < 2; rf++)
    #pragma unroll
    for (int kf = 0; kf < 16; kf++) {
      f32x4 t = __builtin_bit_cast(f32x4, a[rf][kf]);
      asm volatile("" : "+v"(t));
      a[rf][kf] = __builtin_bit_cast(bf16x8, t);
    }

  int labs[8];                               // labels of this lane's 8 rows
  #pragma unroll
  for (int rf = 0; rf < 2; rf++)
    #pragma unroll
    for (int r = 0; r < 4; r++)
      labs[rf * 4 + r] = label[row0 + rf * 16 + 4 * q + r];

  float e[8] = {};                           // per-lane partial exp-sums

  __syncthreads();                           // chunk c0 landed everywhere

  for (int c = c0; c < c1; ++c) {
    const int p = c & 1;
    if (c + 1 < c1) stageB(c + 1, p ^ 1);    // depth-1 prefetch (other buffer)

    f32x4 acc[2][4] = {};
    const unsigned char* bb = &ldsB[p][0];
    #pragma unroll
    for (int ks = 0; ks < 16; ks++) {
      bf16x8 bfr[4];
      #pragma unroll
      for (int cf = 0; cf < 4; cf++)
        bfr[cf] = *(const bf16x8*)(bb + (unsigned)((cf * 16 + ks) * 1024) + (unsigned)lane * 16u);
      #pragma unroll
      for (int rf = 0; rf < 2; rf++)
        #pragma unroll
        for (int cf = 0; cf < 4; cf++)
          acc[rf][cf] = __builtin_amdgcn_mfma_f32_16x16x32_bf16(
              a[rf][ks], bfr[cf], acc[rf][cf], 0, 0, 0);
    }

    // Thin per-chunk epilogue: exp + accumulate into e[8]; rare label store.
    // C/D frag layout: row = 4q + r, col = l15.
    const int ccol = c * 64;
    #pragma unroll
    for (int rf = 0; rf < 2; rf++) {
      #pragma unroll
      for (int r = 0; r < 4; r++) {
        int lab = labs[rf * 4 + r];
        #pragma unroll
        for (int cf = 0; cf < 4; cf++) {
          int col = ccol + cf * 16 + l15;
          float v = acc[rf][cf][r];
          if (col < C_CLS) {
            e[rf * 4 + r] += __expf(v);
            if (col == lab) tbf[row0 + rf * 16 + 4 * q + r] = v;
          }
        }
      }
    }

    __syncthreads();   // vmcnt(0): c+1 landed (covered by chunk compute);
                       // lgkmcnt(0): my buf-p reads retired; barrier: all waves
                       // done with buf p -> next iter may stage c+2 into it.
  }

  // Once-per-block reduce of e over the 16-lane col group + pl store.
  #pragma unroll
  for (int i = 0; i < 8; i++) {
    float s = e[i];
    #pragma unroll
    for (int m = 1; m < 16; m <<= 1) s += __shfl_xor(s, m, 64);
    if (l15 == 0) {
      int grow = row0 + (i >> 2) * 16 + 4 * q + (i & 3);
      pl[(size_t)grow * NGRP + grp] = s;
    }
  }
}

// One thread per row: sum 16 group partials, swap in margin logit, mean-reduce.
__global__ __launch_bounds__(256) void k_reduce(const float* __restrict__ pl,
                                               const float* __restrict__ tv,
                                               const float* __restrict__ tbf,
                                               float* __restrict__ out) {
  int row = blockIdx.x * 256 + threadIdx.x;
  const float4* p = (const float4*)(pl + (size_t)row * NGRP);
  float4 s0 = p[0], s1 = p[1], s2 = p[2], s3 = p[3];
  float S = (s0.x + s0.y + s0.z + s0.w) + (s1.x + s1.y + s1.z + s1.w)
          + (s2.x + s2.y + s2.z + s2.w) + (s3.x + s3.y + s3.z + s3.w);
  float t = tv[row];
  float tb = tbf[row];
  float sint = sqrtf(fmaxf(0.f, 1.f - t * t));
  float cosm = t * COS_M - sint * SIN_M;
  float Sp = S - __expf(tb) + __expf(cosm);   // replace target logit
  float loss = logf(Sp) - cosm;
  #pragma unroll
  for (int m = 32; m > 0; m >>= 1) loss += __shfl_xor(loss, m, 64);
  if ((threadIdx.x & 63) == 0) atomicAdd(out, loss * (1.0f / N_ROWS));
}

extern "C" void kernel_launch(void* const* d_in, const int* in_sizes, int n_in,
                              void* d_out, int out_size, void* d_ws, size_t ws_size,
                              hipStream_t stream) {
  const float* x = (const float*)d_in[0];
  const int* label = (const int*)d_in[1];
  const float* w = (const float*)d_in[2];
  float* out = (float*)d_out;
  char* ws = (char*)d_ws;

  size_t off = 0;
  unsigned short* nx = (unsigned short*)(ws + off); off += (size_t)N_ROWS * E_DIM * 2;  // 4 MB
  unsigned short* nw = (unsigned short*)(ws + off); off += (size_t)C_CLS * E_DIM * 2;   // 51.5 MB
  float* tv  = (float*)(ws + off); off += (size_t)N_ROWS * 4;
  float* tbf = (float*)(ws + off); off += (size_t)N_ROWS * 4;
  float* pl  = (float*)(ws + off); off += (size_t)N_ROWS * NGRP * 4;                    // 256 KB

  hipMemsetAsync(d_out, 0, sizeof(float), stream);
  k_norm_w<<<(C_CLS + 3) / 4, 256, 0, stream>>>(w, nw);
  k_norm_x<<<N_ROWS, 256, 0, stream>>>(x, w, label, nx, tv);
  dim3 g(16, 16);
  k_gemm<<<g, 512, 0, stream>>>(nx, nw, label, pl, tbf);
  k_reduce<<<N_ROWS / 256, 256, 0, stream>>>(pl, tv, tbf, out);
}

// Round 4
// 341.285 us; speedup vs baseline: 1.8889x; 1.1636x over previous
//
#include <hip/hip_runtime.h>
#include <math.h>

#define N_ROWS 4096
#define E_DIM  512
#define C_CLS  50257
#define NCH    786            // ceil(50257/64) col chunks of 64
#define NGRP   16             // col groups (blockIdx.y); pl = [N_ROWS][NGRP]
#define COS_M  (-0.6536436208636119f)   // cos(4.0)
#define SIN_M  (-0.7568024953079282f)   // sin(4.0)
#define EPSN   1e-12f

typedef __bf16 bf16x8 __attribute__((ext_vector_type(8)));
typedef float  f32x4  __attribute__((ext_vector_type(4)));
typedef unsigned short ushort8 __attribute__((ext_vector_type(8)));

__device__ inline unsigned short f2bf(float f) {
  unsigned int u = __float_as_uint(f);
  u += 0x7FFFu + ((u >> 16) & 1u);     // round-to-nearest-even
  return (unsigned short)(u >> 16);
}
__device__ inline float bf2f(unsigned short u) {
  return __uint_as_float((unsigned)u << 16);
}

// w row L2-normalize, wave-private (no barriers): 4 rows/block, 1 wave/row.
__global__ __launch_bounds__(256) void k_norm_w(const float* __restrict__ src,
                                                unsigned short* __restrict__ dst) {
  int row = blockIdx.x * 4 + (threadIdx.x >> 6);
  if (row >= C_CLS) return;
  int lane = threadIdx.x & 63;
  const float4* p = (const float4*)(src + (size_t)row * E_DIM);
  float4 v0 = p[lane * 2], v1 = p[lane * 2 + 1];
  float ss = v0.x*v0.x + v0.y*v0.y + v0.z*v0.z + v0.w*v0.w
           + v1.x*v1.x + v1.y*v1.y + v1.z*v1.z + v1.w*v1.w;
  #pragma unroll
  for (int m = 32; m > 0; m >>= 1) ss += __shfl_xor(ss, m, 64);
  float inv = 1.0f / fmaxf(sqrtf(ss), EPSN);
  ushort8 o;
  o[0]=f2bf(v0.x*inv); o[1]=f2bf(v0.y*inv); o[2]=f2bf(v0.z*inv); o[3]=f2bf(v0.w*inv);
  o[4]=f2bf(v1.x*inv); o[5]=f2bf(v1.y*inv); o[6]=f2bf(v1.z*inv); o[7]=f2bf(v1.w*inv);
  *(ushort8*)(dst + (size_t)row * E_DIM + lane * 8) = o;
}

// x row L2-normalize + precise fp32 target cosine tv + bf16-rounded target
// cosine tb (what the bf16 GEMM produces at the label position, up to fp32
// summation order ~1e-6 -> Δloss ~1e-10). Moving tb here strips all label
// logic from the GEMM hot loop. 1 block/row, 256 thr.
__global__ __launch_bounds__(256) void k_norm_x(const float* __restrict__ x,
                                                const float* __restrict__ w,
                                                const int* __restrict__ label,
                                                unsigned short* __restrict__ nx,
                                                float* __restrict__ tv,
                                                float* __restrict__ tb) {
  int row = blockIdx.x;
  int lab = label[row];
  int tid = threadIdx.x;
  const float2* px = (const float2*)(x + (size_t)row * E_DIM);
  const float2* pw = (const float2*)(w + (size_t)lab * E_DIM);
  float2 a = px[tid], b = pw[tid];
  float sx = a.x*a.x + a.y*a.y;
  float sw = b.x*b.x + b.y*b.y;
  float sd = a.x*b.x + a.y*b.y;
  #pragma unroll
  for (int off = 32; off > 0; off >>= 1) {
    sx += __shfl_down(sx, off, 64);
    sw += __shfl_down(sw, off, 64);
    sd += __shfl_down(sd, off, 64);
  }
  __shared__ float sb[3][4];
  __shared__ float sb2[4];
  if ((tid & 63) == 0) {
    sb[0][tid >> 6] = sx; sb[1][tid >> 6] = sw; sb[2][tid >> 6] = sd;
  }
  __syncthreads();
  float SX = sb[0][0] + sb[0][1] + sb[0][2] + sb[0][3];
  float SW = sb[1][0] + sb[1][1] + sb[1][2] + sb[1][3];
  float invx = 1.0f / fmaxf(sqrtf(SX), EPSN);
  float invw = 1.0f / fmaxf(sqrtf(SW), EPSN);
  ushort2 o;
  o.x = f2bf(a.x * invx);
  o.y = f2bf(a.y * invx);
  ((ushort2*)(nx + (size_t)row * E_DIM))[tid] = o;
  // bf16-rounded dot: same element rounding the GEMM sees (nx and nw paths).
  float s2 = bf2f(o.x) * bf2f(f2bf(b.x * invw))
           + bf2f(o.y) * bf2f(f2bf(b.y * invw));
  #pragma unroll
  for (int off = 32; off > 0; off >>= 1) s2 += __shfl_down(s2, off, 64);
  if ((tid & 63) == 0) sb2[tid >> 6] = s2;
  __syncthreads();
  if (tid == 0) {
    float SD = sb[2][0] + sb[2][1] + sb[2][2] + sb[2][3];
    tv[row] = SD / (fmaxf(sqrtf(SX), EPSN) * fmaxf(sqrtf(SW), EPSN));
    tb[row] = sb2[0] + sb2[1] + sb2[2] + sb2[3];
  }
}

// ---------------------------------------------------------------------------
// Persistent column-streaming GEMM (K=512 register-resident A) + deferred
// exp-sum reduction.
//
// Grid = 16 rtiles x 16 col-groups = 256 blocks = 1 block/CU, one generation.
// Wave owns 32 rows; A-slab (32 rows x K=512 bf16 = 128 VGPR) is loaded via
// INLINE-ASM global_load_dwordx4 — a volatile asm op can neither be sunk into
// the chunk loop nor rematerialized, so the values are guaranteed register-
// resident (round-2/3 lesson: plain loads, even laundered through "+v" asm,
// left the allocator free to re-load 32 KB/wave/chunk from L2 every chunk;
// VGPR_Count=124 < 128 was the tell).
//
// B streams as 64-col x full-K 64 KB chunks through a 2x64 KB LDS double
// buffer via global_load_lds (fragment-ordered, lane-linear 16 B dst -> all
// ds_read_b128 are base+lane*16, 0 bank conflicts). Depth-1 prefetch, ONE
// __syncthreads per chunk (its vmcnt(0) is covered: the prefetch has the
// whole ~7K-cycle chunk to land from L2/L3).
//
// Per-chunk epilogue for interior chunks is ONLY 32 exp + 32 add into
// per-lane partials e[8] — no bounds checks, no label checks (tb moved to
// k_norm_x). Only the final chunk (c == NCH-1) runs the masked variant.
// The 16-lane reduce + pl store happen ONCE per block: pl = [4096][16].
// ---------------------------------------------------------------------------
#define GLDS(gp, lp) __builtin_amdgcn_global_load_lds( \
    (const __attribute__((address_space(1))) void*)(gp), \
    (__attribute__((address_space(3))) void*)(lp), 16, 0, 0)

__global__ __launch_bounds__(512, 2) void k_gemm(const unsigned short* __restrict__ nx,
                                                 const unsigned short* __restrict__ nw,
                                                 float* __restrict__ pl) {
  __shared__ unsigned char ldsB[2][65536];   // 2 x (64 cols x 512 k x 2 B)

  const int rtile = blockIdx.x;              // 0..15
  const int grp   = blockIdx.y;              // 0..15
  const int c0    = grp * 49 + (grp < 2 ? grp : 2);   // chunk range [c0, c1)
  const int c1    = c0 + 49 + (grp < 2 ? 1 : 0);      // groups 0,1 take 50

  const int tid  = threadIdx.x;
  const int wave = tid >> 6;
  const int lane = tid & 63;
  const int q    = lane >> 4;
  const int l15  = lane & 15;
  const int row0 = rtile * 256 + wave * 32;  // wave's first output row

  // Stage chunk c into LDS buffer p. Chunk layout: 64 1-KB fragment chunks,
  // index ch=(cf<<4)|kf covers cols [cf*16,+16) x k [kf*32,+32); lane (q,l15)
  // supplies col cf*16+l15, k kf*32+q*8..+7 (16 B) -> lands at base+lane*16.
  auto stageB = [&](int c, int p) {
    unsigned cb = (unsigned)c * 64u;
    #pragma unroll
    for (int i = 0; i < 8; i++) {
      int ch = wave * 8 + i;                 // wave-uniform
      unsigned col = cb + (unsigned)(((ch >> 4) << 4) + l15);
      if (col >= C_CLS) col = C_CLS - 1;     // clamp; masked in tail epilogue
      unsigned off = col * (unsigned)E_DIM + (unsigned)((ch & 15) * 32 + q * 8);
      GLDS(nw + off, &ldsB[p][ch * 1024]);
    }
  };

  // Issue first B-chunk stage, then load A-slab while it flies.
  stageB(c0, c0 & 1);

  // A-slab: 32 rows x K=512 in registers for the whole block, loaded with
  // inline asm so the compiler cannot sink or rematerialize the loads.
  f32x4 araw[2][16];
  #pragma unroll
  for (int rf = 0; rf < 2; rf++)
    #pragma unroll
    for (int kf = 0; kf < 16; kf++) {
      const unsigned short* pa = nx + (size_t)(row0 + rf * 16 + l15) * E_DIM
                                    + kf * 32 + q * 8;
      asm volatile("global_load_dwordx4 %0, %1, off"
                   : "=v"(araw[rf][kf]) : "v"(pa));
    }
  asm volatile("s_waitcnt vmcnt(0)" ::: "memory");
  bf16x8 a[2][16];
  #pragma unroll
  for (int rf = 0; rf < 2; rf++)
    #pragma unroll
    for (int kf = 0; kf < 16; kf++)
      a[rf][kf] = __builtin_bit_cast(bf16x8, araw[rf][kf]);

  float e[8] = {};                           // per-lane partial exp-sums

  __syncthreads();                           // chunk c0 landed everywhere

  for (int c = c0; c < c1; ++c) {
    const int p = c & 1;
    if (c + 1 < c1) stageB(c + 1, p ^ 1);    // depth-1 prefetch (other buffer)

    f32x4 acc[2][4] = {};
    const unsigned char* bb = &ldsB[p][0];
    #pragma unroll
    for (int ks = 0; ks < 16; ks++) {
      bf16x8 bfr[4];
      #pragma unroll
      for (int cf = 0; cf < 4; cf++)
        bfr[cf] = *(const bf16x8*)(bb + (unsigned)((cf * 16 + ks) * 1024) + (unsigned)lane * 16u);
      #pragma unroll
      for (int rf = 0; rf < 2; rf++)
        #pragma unroll
        for (int cf = 0; cf < 4; cf++)
          acc[rf][cf] = __builtin_amdgcn_mfma_f32_16x16x32_bf16(
              a[rf][ks], bfr[cf], acc[rf][cf], 0, 0, 0);
    }

    // Thin per-chunk epilogue: exp + accumulate; compares only in the tail.
    if (c != NCH - 1) {
      #pragma unroll
      for (int rf = 0; rf < 2; rf++)
        #pragma unroll
        for (int r = 0; r < 4; r++)
          #pragma unroll
          for (int cf = 0; cf < 4; cf++)
            e[rf * 4 + r] += __expf(acc[rf][cf][r]);
    } else {
      const int ccol = c * 64;
      #pragma unroll
      for (int rf = 0; rf < 2; rf++)
        #pragma unroll
        for (int r = 0; r < 4; r++)
          #pragma unroll
          for (int cf = 0; cf < 4; cf++) {
            int col = ccol + cf * 16 + l15;
            if (col < C_CLS) e[rf * 4 + r] += __expf(acc[rf][cf][r]);
          }
    }

    __syncthreads();   // vmcnt(0): c+1 landed (covered by chunk compute);
                       // lgkmcnt(0): my buf-p reads retired; barrier: all waves
                       // done with buf p -> next iter may stage c+2 into it.
  }

  // Once-per-block reduce of e over the 16-lane col group + pl store.
  #pragma unroll
  for (int i = 0; i < 8; i++) {
    float s = e[i];
    #pragma unroll
    for (int m = 1; m < 16; m <<= 1) s += __shfl_xor(s, m, 64);
    if (l15 == 0) {
      int grow = row0 + (i >> 2) * 16 + 4 * q + (i & 3);
      pl[(size_t)grow * NGRP + grp] = s;
    }
  }
}

// One thread per row: sum 16 group partials, swap in margin logit, mean-reduce.
__global__ __launch_bounds__(256) void k_reduce(const float* __restrict__ pl,
                                               const float* __restrict__ tv,
                                               const float* __restrict__ tb,
                                               float* __restrict__ out) {
  int row = blockIdx.x * 256 + threadIdx.x;
  const float4* p = (const float4*)(pl + (size_t)row * NGRP);
  float4 s0 = p[0], s1 = p[1], s2 = p[2], s3 = p[3];
  float S = (s0.x + s0.y + s0.z + s0.w) + (s1.x + s1.y + s1.z + s1.w)
          + (s2.x + s2.y + s2.z + s2.w) + (s3.x + s3.y + s3.z + s3.w);
  float t = tv[row];
  float tbl = tb[row];
  float sint = sqrtf(fmaxf(0.f, 1.f - t * t));
  float cosm = t * COS_M - sint * SIN_M;
  float Sp = S - __expf(tbl) + __expf(cosm);  // replace target logit
  float loss = logf(Sp) - cosm;
  #pragma unroll
  for (int m = 32; m > 0; m >>= 1) loss += __shfl_xor(loss, m, 64);
  if ((threadIdx.x & 63) == 0) atomicAdd(out, loss * (1.0f / N_ROWS));
}

extern "C" void kernel_launch(void* const* d_in, const int* in_sizes, int n_in,
                              void* d_out, int out_size, void* d_ws, size_t ws_size,
                              hipStream_t stream) {
  const float* x = (const float*)d_in[0];
  const int* label = (const int*)d_in[1];
  const float* w = (const float*)d_in[2];
  float* out = (float*)d_out;
  char* ws = (char*)d_ws;

  size_t off = 0;
  unsigned short* nx = (unsigned short*)(ws + off); off += (size_t)N_ROWS * E_DIM * 2;  // 4 MB
  unsigned short* nw = (unsigned short*)(ws + off); off += (size_t)C_CLS * E_DIM * 2;   // 51.5 MB
  float* tv  = (float*)(ws + off); off += (size_t)N_ROWS * 4;
  float* tb  = (float*)(ws + off); off += (size_t)N_ROWS * 4;
  float* pl  = (float*)(ws + off); off += (size_t)N_ROWS * NGRP * 4;                    // 256 KB

  hipMemsetAsync(d_out, 0, sizeof(float), stream);
  k_norm_w<<<(C_CLS + 3) / 4, 256, 0, stream>>>(w, nw);
  k_norm_x<<<N_ROWS, 256, 0, stream>>>(x, w, label, nx, tv, tb);
  dim3 g(16, 16);
  k_gemm<<<g, 512, 0, stream>>>(nx, nw, pl);
  k_reduce<<<N_ROWS / 256, 256, 0, stream>>>(pl, tv, tb, out);
}